// Round 5
// baseline (1617.507 us; speedup 1.0000x reference)
//
#include <hip/hip_runtime.h>
#include <hip/hip_cooperative_groups.h>
#include <stdint.h>

namespace cg = cooperative_groups;

#define B_ROWS 131072
#define SCALE 0.0625f
#define LN_EPS 1e-5f
#define ATTN_EPS 1e-8f

#define BIG_BLOCKS 1024
#define ROWS_PER_BLOCK (B_ROWS / BIG_BLOCKS)   // 128
#define ROWS_PER_WAVE  (ROWS_PER_BLOCK / 4)    // 32

// ---- workspace layout (float offsets) ----
#define WS_PARTU 0                     // 1024*4096 = 4194304
#define WS_PARTS 4194304               // 1024*16   = 16384
#define WS_U     4210688               // 4096
#define WS_S     4214784               // 64
#define WS_SLOTS 4214848               // 4096
#define WS_MID   4218944               // 4096
#define WS_GX    4223040               // 12288
#define WS_GH    4235328               // 12288
#define WS_H1    4247616               // 4096
#define WS_QKG   4251712               // 4096
#define WS_QB    4255808               // 64
#define WS_WIHV  4255872               // 196608
#define WS_BGX   4452480               // 768
#define WS_WQKG  4453248               // 65536
#define WS_U2G   4518784               // 256
#define WS_U1    4519040               // 256
#define WS_C1    4519296               // 1
// total ~4519297 floats ~ 18.1 MB

// =====================================================================
// K_pre1: weight compositions (fp32 inputs)
// =====================================================================
__global__ __launch_bounds__(256) void k_pre1(
    const float* __restrict__ Wq, const float* __restrict__ bq,
    const float* __restrict__ Wk, const float* __restrict__ bk,
    const float* __restrict__ Wv, const float* __restrict__ bv,
    const float* __restrict__ W_ih, const float* __restrict__ b_ih,
    const float* __restrict__ g_in, const float* __restrict__ be_in,
    float* __restrict__ ws)
{
  int bid = blockIdx.x, t = threadIdx.x;
  if (bid < 48) {
    int j0 = bid * 16;
    float acc[16];
#pragma unroll
    for (int r = 0; r < 16; r++) acc[r] = 0.f;
    int d = t;
    for (int dd = 0; dd < 256; dd++) {
      float v = Wv[dd * 256 + d];
#pragma unroll
      for (int r = 0; r < 16; r++)
        acc[r] = fmaf(W_ih[(j0 + r) * 256 + dd], v, acc[r]);
    }
#pragma unroll
    for (int r = 0; r < 16; r++) ws[WS_WIHV + (j0 + r) * 256 + d] = acc[r];
    if (t < 16) {
      int j = j0 + t;
      float a = b_ih[j];
      for (int dd = 0; dd < 256; dd++)
        a = fmaf(W_ih[j * 256 + dd], bv[dd], a);
      ws[WS_BGX + j] = a;
    }
  } else if (bid < 80) {
    int c0 = (bid - 48) * 8;
    float acc[8];
#pragma unroll
    for (int r = 0; r < 8; r++) acc[r] = 0.f;
    int d = t;
    for (int i = 0; i < 256; i++) {
      float wq = Wq[i * 256 + d];
#pragma unroll
      for (int r = 0; r < 8; r++)
        acc[r] = fmaf(wq, Wk[i * 256 + c0 + r], acc[r]);
    }
#pragma unroll
    for (int r = 0; r < 8; r++) {
      float gc = g_in[c0 + r];
      ws[WS_WQKG + (c0 + r) * 256 + d] = SCALE * gc * acc[r];
    }
    if (t < 8) {
      int c = c0 + t;
      float a = 0.f;
      for (int i = 0; i < 256; i++)
        a = fmaf(bq[i], Wk[i * 256 + c], a);
      ws[WS_U2G + c] = SCALE * g_in[c] * a;
    }
  } else {
    __shared__ __align__(16) float t2[256];
    int j = t;
    float a = 0.f;
    for (int dp = 0; dp < 256; dp++)
      a = fmaf(Wk[j * 256 + dp], be_in[dp], a);
    t2[j] = a + bk[j];
    __syncthreads();
    int d = t;
    float u = 0.f;
    for (int i = 0; i < 256; i++)
      u = fmaf(Wq[i * 256 + d], t2[i], u);
    ws[WS_U1 + d] = u;
    if (t == 0) {
      float c = 0.f;
      for (int i = 0; i < 256; i++) c = fmaf(bq[i], t2[i], c);
      ws[WS_C1] = c;
    }
  }
}

// =====================================================================
// K_qkg (standalone, init only): slots = mu + sigma*noise; LN; qkg, qb.
// =====================================================================
__global__ __launch_bounds__(256) void k_qkg(
    const float* __restrict__ noise, const float* __restrict__ mu,
    const float* __restrict__ sigma, const float* __restrict__ g_s,
    const float* __restrict__ be_s, float* __restrict__ ws)
{
  __shared__ __align__(16) float sS[16 * 260];
  __shared__ __align__(16) float sAux[512];
  __shared__ __align__(16) float sStat[32];
  int bid = blockIdx.x, t = threadIdx.x;
  for (int n = 0; n < 16; n++) {
    float v = fmaf(sigma[t], noise[n * 256 + t], mu[t]);
    sS[n * 260 + t] = v;
    if (bid == 0) ws[WS_SLOTS + n * 256 + t] = v;
  }
  __syncthreads();
  { int n = t >> 4, c = t & 15;
    float s1 = 0.f, s2 = 0.f;
    for (int k = 0; k < 16; k++) {
      float x = sS[n * 260 + c * 16 + k];
      s1 += x; s2 = fmaf(x, x, s2);
    }
    sAux[n * 16 + c] = s1; sAux[256 + n * 16 + c] = s2; }
  __syncthreads();
  if (t < 16) {
    float s1 = 0.f, s2 = 0.f;
    for (int c = 0; c < 16; c++) { s1 += sAux[t * 16 + c]; s2 += sAux[256 + t * 16 + c]; }
    float m = s1 * (1.f / 256.f);
    float v = fmaxf(fmaf(-m, m, s2 * (1.f / 256.f)), 0.f);
    sStat[t] = m; sStat[16 + t] = rsqrtf(v + LN_EPS);
  }
  __syncthreads();
  { float gs = g_s[t], bs = be_s[t];
    for (int n = 0; n < 16; n++) {
      float m = sStat[n], rs = sStat[16 + n];
      sS[n * 260 + t] = fmaf((sS[n * 260 + t] - m) * rs, gs, bs);
    } }
  __syncthreads();
  if (bid < 64) {
    int cr = t >> 6, n = (t >> 2) & 15, ks = t & 3;
    int c = bid * 4 + cr;
    const float* wrow = ws + WS_WQKG + c * 256 + ks * 64;
    const float* srow = &sS[n * 260 + ks * 64];
    float acc = 0.f;
#pragma unroll
    for (int i = 0; i < 16; i++) {
      float4 w = *(const float4*)(wrow + i * 4);
      float4 s4 = *(const float4*)(srow + i * 4);
      acc = fmaf(w.x, s4.x, fmaf(w.y, s4.y, fmaf(w.z, s4.z, fmaf(w.w, s4.w, acc))));
    }
    sAux[t] = acc;
    __syncthreads();
    if (t < 64) {
      int cr2 = t >> 4, n2 = t & 15;
      int c2 = bid * 4 + cr2;
      int b = cr2 * 64 + n2 * 4;
      float s = sAux[b] + sAux[b + 1] + sAux[b + 2] + sAux[b + 3];
      ws[WS_QKG + n2 * 256 + c2] = s + ws[WS_U2G + c2];
    }
  } else {
    int n = t >> 4, ks = t & 15;
    float acc = 0.f;
    for (int k = 0; k < 16; k++)
      acc = fmaf(sS[n * 260 + ks * 16 + k], ws[WS_U1 + ks * 16 + k], acc);
    sAux[t] = acc;
    __syncthreads();
    if (t < 16) {
      float s = 0.f;
      for (int k = 0; k < 16; k++) s += sAux[t * 16 + k];
      ws[WS_QB + t] = SCALE * (s + ws[WS_C1]);
    }
  }
}

// =====================================================================
// K_big: wave-per-row LN + dots + softmax + weighted accumulate.
// Epilogue: 16KB LDS 4-round wave accumulate, then PLAIN partial-slice
// store (NO atomics — R4 showed cross-XCD fp32 atomics cost ~0.9GB HBM).
// =====================================================================
__global__ __launch_bounds__(256, 4) void k_big(
    const float* __restrict__ X, float* __restrict__ ws)
{
  __shared__ __align__(16) float red[16 * 256];   // 16 KB
  __shared__ __align__(16) float redS[64];
  int t = threadIdx.x;
  int wave = t >> 6, lane = t & 63;
  int p = lane >> 4, g = lane & 15;

  const float* qkg = ws + WS_QKG;
  float qw[4][16];
  float qs[4];
#pragma unroll
  for (int i = 0; i < 4; i++) {
    const float* rp = qkg + (4 * p + i) * 256 + g * 16;
#pragma unroll
    for (int jq = 0; jq < 4; jq++) {
      float4 v4 = *(const float4*)(rp + 4 * jq);
      qw[i][4 * jq + 0] = v4.x; qw[i][4 * jq + 1] = v4.y;
      qw[i][4 * jq + 2] = v4.z; qw[i][4 * jq + 3] = v4.w;
    }
    float s = 0.f;
#pragma unroll
    for (int j = 0; j < 16; j++) s += qw[i][j];
    qs[i] = s;
  }
#pragma unroll
  for (int m = 1; m <= 8; m <<= 1) {
#pragma unroll
    for (int i = 0; i < 4; i++) qs[i] += __shfl_xor(qs[i], m);
  }
  float qb0[4];
  {
    float4 q4 = *(const float4*)(ws + WS_QB + 4 * p);
    qb0[0] = q4.x; qb0[1] = q4.y; qb0[2] = q4.z; qb0[3] = q4.w;
  }

  float P[4][16];
#pragma unroll
  for (int i = 0; i < 4; i++)
#pragma unroll
    for (int j = 0; j < 16; j++) P[i][j] = 0.f;
  float Q[4] = {0.f, 0.f, 0.f, 0.f};
  float Sa[4] = {0.f, 0.f, 0.f, 0.f};

  size_t rowbase = (size_t)blockIdx.x * ROWS_PER_BLOCK + (size_t)wave * ROWS_PER_WAVE;
  const float* cur = X + rowbase * 256 + g * 16;
  float4 va = *(const float4*)cur;
  float4 vb = *(const float4*)(cur + 4);
  float4 vc = *(const float4*)(cur + 8);
  float4 vd = *(const float4*)(cur + 12);

#pragma unroll 1
  for (int r = 0; r < ROWS_PER_WAVE; r++) {
    const float* nxt = (r < ROWS_PER_WAVE - 1) ? (cur + 256) : cur;
    float4 na = *(const float4*)nxt;
    float4 nb = *(const float4*)(nxt + 4);
    float4 nc = *(const float4*)(nxt + 8);
    float4 nd = *(const float4*)(nxt + 12);

    float x[16];
    x[0] = va.x; x[1] = va.y; x[2] = va.z; x[3] = va.w;
    x[4] = vb.x; x[5] = vb.y; x[6] = vb.z; x[7] = vb.w;
    x[8] = vc.x; x[9] = vc.y; x[10] = vc.z; x[11] = vc.w;
    x[12] = vd.x; x[13] = vd.y; x[14] = vd.z; x[15] = vd.w;

    float s1 = 0.f, s2 = 0.f;
#pragma unroll
    for (int j = 0; j < 16; j++) { s1 += x[j]; s2 = fmaf(x[j], x[j], s2); }
#pragma unroll
    for (int m = 1; m <= 8; m <<= 1) {
      s1 += __shfl_xor(s1, m);
      s2 += __shfl_xor(s2, m);
    }
    float mean = s1 * (1.f / 256.f);
    float var = fmaxf(fmaf(-mean, mean, s2 * (1.f / 256.f)), 0.f);
    float rs = rsqrtf(var + LN_EPS);
    float mrs = mean * rs;

    float d0 = 0.f, d1 = 0.f, d2 = 0.f, d3 = 0.f;
#pragma unroll
    for (int j = 0; j < 16; j++) {
      d0 = fmaf(qw[0][j], x[j], d0);
      d1 = fmaf(qw[1][j], x[j], d1);
      d2 = fmaf(qw[2][j], x[j], d2);
      d3 = fmaf(qw[3][j], x[j], d3);
    }
#pragma unroll
    for (int m = 1; m <= 8; m <<= 1) {
      d0 += __shfl_xor(d0, m); d1 += __shfl_xor(d1, m);
      d2 += __shfl_xor(d2, m); d3 += __shfl_xor(d3, m);
    }
    float dsc[4];
    dsc[0] = fmaf(rs, d0, fmaf(-mrs, qs[0], qb0[0]));
    dsc[1] = fmaf(rs, d1, fmaf(-mrs, qs[1], qb0[1]));
    dsc[2] = fmaf(rs, d2, fmaf(-mrs, qs[2], qb0[2]));
    dsc[3] = fmaf(rs, d3, fmaf(-mrs, qs[3], qb0[3]));

    float mx = fmaxf(fmaxf(dsc[0], dsc[1]), fmaxf(dsc[2], dsc[3]));
    mx = fmaxf(mx, __shfl_xor(mx, 16));
    mx = fmaxf(mx, __shfl_xor(mx, 32));
    float e[4];
#pragma unroll
    for (int i = 0; i < 4; i++) e[i] = __expf(dsc[i] - mx);
    float se = e[0] + e[1] + e[2] + e[3];
    se += __shfl_xor(se, 16);
    se += __shfl_xor(se, 32);
    float inv = 1.0f / se;
    float a0[4], ar[4];
#pragma unroll
    for (int i = 0; i < 4; i++) {
      a0[i] = fmaf(e[i], inv, ATTN_EPS);
      ar[i] = a0[i] * rs;
    }
#pragma unroll
    for (int j = 0; j < 16; j++) {
      P[0][j] = fmaf(ar[0], x[j], P[0][j]);
      P[1][j] = fmaf(ar[1], x[j], P[1][j]);
      P[2][j] = fmaf(ar[2], x[j], P[2][j]);
      P[3][j] = fmaf(ar[3], x[j], P[3][j]);
    }
#pragma unroll
    for (int i = 0; i < 4; i++) {
      Q[i] = fmaf(a0[i], mrs, Q[i]);
      Sa[i] += a0[i];
    }
    va = na; vb = nb; vc = nc; vd = nd; cur = nxt;
  }

  // ---- epilogue: block-reduce U = P - Q into 16KB LDS, plain store ----
  if (g == 0) {
#pragma unroll
    for (int i = 0; i < 4; i++) redS[wave * 16 + 4 * p + i] = Sa[i];
  }
#pragma unroll 1
  for (int w = 0; w < 4; w++) {
    if (w) __syncthreads();
    if (wave == w) {
#pragma unroll
      for (int i = 0; i < 4; i++) {
#pragma unroll
        for (int jq = 0; jq < 4; jq++) {
          int idx = (4 * p + i) * 256 + g * 16 + jq * 4;
          float4 v4;
          v4.x = P[i][4 * jq + 0] - Q[i]; v4.y = P[i][4 * jq + 1] - Q[i];
          v4.z = P[i][4 * jq + 2] - Q[i]; v4.w = P[i][4 * jq + 3] - Q[i];
          if (w == 0) {
            *(float4*)&red[idx] = v4;
          } else {
            float4 o = *(const float4*)&red[idx];
            v4.x += o.x; v4.y += o.y; v4.z += o.z; v4.w += o.w;
            *(float4*)&red[idx] = v4;
          }
        }
      }
    }
  }
  __syncthreads();
#pragma unroll
  for (int k = 0; k < 16; k++) {
    int idx = k * 256 + t;
    ws[WS_PARTU + (size_t)blockIdx.x * 4096 + idx] = red[idx];
  }
  if (t < 16) {
    float sv = redS[t] + redS[16 + t] + redS[32 + t] + redS[48 + t];
    ws[WS_PARTS + blockIdx.x * 16 + t] = sv;
  }
}

// =====================================================================
// K_chain (cooperative, 128 blocks x 256):
//  R: reduce 1024 partial slices -> U[16][256], S[16]
//  G: gx/gh GEMMs   M: GRU+LN+W1   F: W2+residual (-> slots, out)
//  Q (skip if last): LN(slots)+qkg/qb for next iteration
// =====================================================================
__global__ __launch_bounds__(256) void k_chain(
    const float* __restrict__ W_hh, const float* __restrict__ b_hh,
    const float* __restrict__ g_in, const float* __restrict__ be_in,
    const float* __restrict__ W1, const float* __restrict__ b1,
    const float* __restrict__ g_f, const float* __restrict__ be_f,
    const float* __restrict__ W2, const float* __restrict__ b2v,
    const float* __restrict__ g_s, const float* __restrict__ be_s,
    float* __restrict__ out, float* __restrict__ ws, int last)
{
  cg::grid_group grid = cg::this_grid();
  __shared__ __align__(16) float sBuf[16 * 260];
  __shared__ __align__(16) float sAux[512];
  __shared__ __align__(16) float sStat[32];
  __shared__ __align__(16) float sRed[256];
  int bid = blockIdx.x, t = threadIdx.x;

  // ---- stage R: partial reduce ----
  {
    int el = t & 31, wg = t >> 5;           // 8 groups x 128 slices
    int e = bid * 32 + el;
    float acc = 0.f;
#pragma unroll 8
    for (int k = 0; k < 128; k++)
      acc += ws[WS_PARTU + (size_t)(wg * 128 + k) * 4096 + e];
    sRed[t] = acc;
    float a = 0.f;
    if (bid == 127) {
      int n = t & 15, wg2 = t >> 4;         // 16 groups x 64 slices
      for (int k = 0; k < 64; k++)
        a += ws[WS_PARTS + (wg2 * 64 + k) * 16 + n];
    }
    sAux[t] = a;
    __syncthreads();
    if (t < 32) {
      float s = 0.f;
#pragma unroll
      for (int w = 0; w < 8; w++) s += sRed[w * 32 + t];
      ws[WS_U + bid * 32 + t] = s;
    }
    if (bid == 127 && t < 16) {
      float s = 0.f;
#pragma unroll
      for (int w = 0; w < 16; w++) s += sAux[w * 16 + t];
      ws[WS_S + t] = s;
    }
  }
  __threadfence();
  grid.sync();

  // ---- stage G: gx (bid<64) / gh (bid>=64) ----
  {
    bool isgx = bid < 64;
    if (t < 16) sStat[t] = 1.0f / ws[WS_S + t];
    __syncthreads();
    if (isgx) {
      float gi = g_in[t], bi = be_in[t];
      for (int n = 0; n < 16; n++)
        sBuf[n * 260 + t] = fmaf(gi * ws[WS_U + n * 256 + t], sStat[n], bi);
    } else {
      for (int n = 0; n < 16; n++)
        sBuf[n * 260 + t] = ws[WS_SLOTS + n * 256 + t];
    }
    __syncthreads();
    int jr = t >> 4, n = t & 15;
    if (jr < 12) {
      int j = (isgx ? bid : bid - 64) * 12 + jr;
      const float* srow = &sBuf[n * 260];
      const float* wrow = isgx ? (ws + WS_WIHV + j * 256) : (W_hh + j * 256);
      float acc = isgx ? ws[WS_BGX + j] : b_hh[j];
#pragma unroll 8
      for (int k = 0; k < 64; k++) {
        float4 w = *(const float4*)(wrow + k * 4);
        float4 s4 = *(const float4*)(srow + k * 4);
        acc = fmaf(w.x, s4.x, fmaf(w.y, s4.y, fmaf(w.z, s4.z, fmaf(w.w, s4.w, acc))));
      }
      if (isgx) ws[WS_GX + n * 768 + j] = acc;
      else      ws[WS_GH + n * 768 + j] = acc;
    }
  }
  __threadfence();
  grid.sync();

  // ---- stage M: GRU gates -> mid; LN(g_f); h1 = relu(@W1.T + b1) ----
  if (bid < 64) {
    for (int n = 0; n < 16; n++) {
      float xr = ws[WS_GX + n * 768 + t],       hr = ws[WS_GH + n * 768 + t];
      float xz = ws[WS_GX + n * 768 + 256 + t], hz = ws[WS_GH + n * 768 + 256 + t];
      float xn = ws[WS_GX + n * 768 + 512 + t], hn = ws[WS_GH + n * 768 + 512 + t];
      float sp = ws[WS_SLOTS + n * 256 + t];
      float r = 1.f / (1.f + __expf(-(xr + hr)));
      float z = 1.f / (1.f + __expf(-(xz + hz)));
      float nn = tanhf(fmaf(r, hn, xn));
      float mid = fmaf(z, sp - nn, nn);
      sBuf[n * 260 + t] = mid;
      if (bid == 0) ws[WS_MID + n * 256 + t] = mid;
    }
    __syncthreads();
    { int n = t >> 4, c = t & 15;
      float s1 = 0.f, s2 = 0.f;
      for (int k = 0; k < 16; k++) {
        float x = sBuf[n * 260 + c * 16 + k];
        s1 += x; s2 = fmaf(x, x, s2);
      }
      sAux[n * 16 + c] = s1; sAux[256 + n * 16 + c] = s2; }
    __syncthreads();
    if (t < 16) {
      float s1 = 0.f, s2 = 0.f;
      for (int c = 0; c < 16; c++) { s1 += sAux[t * 16 + c]; s2 += sAux[256 + t * 16 + c]; }
      float m = s1 * (1.f / 256.f);
      float v = fmaxf(fmaf(-m, m, s2 * (1.f / 256.f)), 0.f);
      sStat[t] = m; sStat[16 + t] = rsqrtf(v + LN_EPS);
    }
    __syncthreads();
    { float gf = g_f[t], bf = be_f[t];
      for (int n = 0; n < 16; n++) {
        float m = sStat[n], rs = sStat[16 + n];
        sBuf[n * 260 + t] = fmaf((sBuf[n * 260 + t] - m) * rs, gf, bf);
      } }
    __syncthreads();
    int jr = t >> 6, n = (t >> 2) & 15, ks = t & 3;
    int j = bid * 4 + jr;
    const float* wrow = W1 + j * 256 + ks * 64;
    const float* srow = &sBuf[n * 260 + ks * 64];
    float acc = 0.f;
#pragma unroll
    for (int k = 0; k < 16; k++) {
      float4 w = *(const float4*)(wrow + k * 4);
      float4 s4 = *(const float4*)(srow + k * 4);
      acc = fmaf(w.x, s4.x, fmaf(w.y, s4.y, fmaf(w.z, s4.z, fmaf(w.w, s4.w, acc))));
    }
    sAux[t] = acc;
    __syncthreads();
    if (t < 64) {
      int jr2 = t >> 4, n2 = t & 15;
      int j2 = bid * 4 + jr2;
      int b = jr2 * 64 + n2 * 4;
      float s = sAux[b] + sAux[b + 1] + sAux[b + 2] + sAux[b + 3] + b1[j2];
      ws[WS_H1 + n2 * 256 + j2] = fmaxf(s, 0.f);
    }
  }
  __threadfence();
  grid.sync();

  // ---- stage F: ff = h1@W2.T + b2; slots += -> ws.slots, out ----
  if (bid < 64) {
    for (int n = 0; n < 16; n++)
      sBuf[n * 260 + t] = ws[WS_H1 + n * 256 + t];
    __syncthreads();
    int dr = t >> 6, n = (t >> 2) & 15, ks = t & 3;
    int d = bid * 4 + dr;
    const float* wrow = W2 + d * 256 + ks * 64;
    const float* srow = &sBuf[n * 260 + ks * 64];
    float acc = 0.f;
#pragma unroll
    for (int k = 0; k < 16; k++) {
      float4 w = *(const float4*)(wrow + k * 4);
      float4 s4 = *(const float4*)(srow + k * 4);
      acc = fmaf(w.x, s4.x, fmaf(w.y, s4.y, fmaf(w.z, s4.z, fmaf(w.w, s4.w, acc))));
    }
    sAux[t] = acc;
    __syncthreads();
    if (t < 64) {
      int dr2 = t >> 4, n2 = t & 15;
      int d2 = bid * 4 + dr2;
      int b = dr2 * 64 + n2 * 4;
      float s = sAux[b] + sAux[b + 1] + sAux[b + 2] + sAux[b + 3]
              + b2v[d2] + ws[WS_MID + n2 * 256 + d2];
      ws[WS_SLOTS + n2 * 256 + d2] = s;
      out[n2 * 256 + d2] = s;
    }
  }
  if (last) return;
  __threadfence();
  grid.sync();

  // ---- stage Q: LN(slots) -> qkg, qb for next iteration ----
  if (bid <= 64) {
    for (int n = 0; n < 16; n++)
      sBuf[n * 260 + t] = ws[WS_SLOTS + n * 256 + t];
    __syncthreads();
    { int n = t >> 4, c = t & 15;
      float s1 = 0.f, s2 = 0.f;
      for (int k = 0; k < 16; k++) {
        float x = sBuf[n * 260 + c * 16 + k];
        s1 += x; s2 = fmaf(x, x, s2);
      }
      sAux[n * 16 + c] = s1; sAux[256 + n * 16 + c] = s2; }
    __syncthreads();
    if (t < 16) {
      float s1 = 0.f, s2 = 0.f;
      for (int c = 0; c < 16; c++) { s1 += sAux[t * 16 + c]; s2 += sAux[256 + t * 16 + c]; }
      float m = s1 * (1.f / 256.f);
      float v = fmaxf(fmaf(-m, m, s2 * (1.f / 256.f)), 0.f);
      sStat[t] = m; sStat[16 + t] = rsqrtf(v + LN_EPS);
    }
    __syncthreads();
    { float gs = g_s[t], bs = be_s[t];
      for (int n = 0; n < 16; n++) {
        float m = sStat[n], rs = sStat[16 + n];
        sBuf[n * 260 + t] = fmaf((sBuf[n * 260 + t] - m) * rs, gs, bs);
      } }
    __syncthreads();
    if (bid < 64) {
      int cr = t >> 6, n = (t >> 2) & 15, ks = t & 3;
      int c = bid * 4 + cr;
      const float* wrow = ws + WS_WQKG + c * 256 + ks * 64;
      const float* srow = &sBuf[n * 260 + ks * 64];
      float acc = 0.f;
#pragma unroll
      for (int i = 0; i < 16; i++) {
        float4 w = *(const float4*)(wrow + i * 4);
        float4 s4 = *(const float4*)(srow + i * 4);
        acc = fmaf(w.x, s4.x, fmaf(w.y, s4.y, fmaf(w.z, s4.z, fmaf(w.w, s4.w, acc))));
      }
      sAux[t] = acc;
      __syncthreads();
      if (t < 64) {
        int cr2 = t >> 4, n2 = t & 15;
        int c2 = bid * 4 + cr2;
        int b = cr2 * 64 + n2 * 4;
        float s = sAux[b] + sAux[b + 1] + sAux[b + 2] + sAux[b + 3];
        ws[WS_QKG + n2 * 256 + c2] = s + ws[WS_U2G + c2];
      }
    } else {
      int n = t >> 4, ks = t & 15;
      float acc = 0.f;
      for (int k = 0; k < 16; k++)
        acc = fmaf(sBuf[n * 260 + ks * 16 + k], ws[WS_U1 + ks * 16 + k], acc);
      sAux[t] = acc;
      __syncthreads();
      if (t < 16) {
        float s = 0.f;
        for (int k = 0; k < 16; k++) s += sAux[t * 16 + k];
        ws[WS_QB + t] = SCALE * (s + ws[WS_C1]);
      }
    }
  }
}

// =====================================================================
extern "C" void kernel_launch(void* const* d_in, const int* in_sizes, int n_in,
                              void* d_out, int out_size, void* d_ws, size_t ws_size,
                              hipStream_t stream)
{
  (void)in_sizes; (void)n_in; (void)out_size; (void)ws_size;
  const float* inputs = (const float*)d_in[0];
  const float* noise  = (const float*)d_in[1];
  const float* mu     = (const float*)d_in[2];
  const float* sigma  = (const float*)d_in[3];
  const float* Wq     = (const float*)d_in[4];
  const float* bq     = (const float*)d_in[5];
  const float* Wk     = (const float*)d_in[6];
  const float* bk     = (const float*)d_in[7];
  const float* Wv     = (const float*)d_in[8];
  const float* bv     = (const float*)d_in[9];
  const float* W_ih   = (const float*)d_in[10];
  const float* W_hh   = (const float*)d_in[11];
  const float* b_ih   = (const float*)d_in[12];
  const float* b_hh   = (const float*)d_in[13];
  const float* W1     = (const float*)d_in[14];
  const float* b1     = (const float*)d_in[15];
  const float* W2     = (const float*)d_in[16];
  const float* b2     = (const float*)d_in[17];
  const float* g_in   = (const float*)d_in[18];
  const float* be_in  = (const float*)d_in[19];
  const float* g_s    = (const float*)d_in[20];
  const float* be_s   = (const float*)d_in[21];
  const float* g_f    = (const float*)d_in[22];
  const float* be_f   = (const float*)d_in[23];
  float* ws = (float*)d_ws;
  float* out = (float*)d_out;

  hipLaunchKernelGGL(k_pre1, dim3(81), dim3(256), 0, stream,
                     Wq, bq, Wk, bk, Wv, bv, W_ih, b_ih, g_in, be_in, ws);
  hipLaunchKernelGGL(k_qkg, dim3(65), dim3(256), 0, stream,
                     noise, mu, sigma, g_s, be_s, ws);
  for (int it = 0; it < 3; it++) {
    hipLaunchKernelGGL(k_big, dim3(BIG_BLOCKS), dim3(256), 0, stream, inputs, ws);
    int last = (it == 2) ? 1 : 0;
    void* args[] = {
      (void*)&W_hh, (void*)&b_hh, (void*)&g_in, (void*)&be_in,
      (void*)&W1, (void*)&b1, (void*)&g_f, (void*)&be_f,
      (void*)&W2, (void*)&b2, (void*)&g_s, (void*)&be_s,
      (void*)&out, (void*)&ws, (void*)&last
    };
    hipLaunchCooperativeKernel((void*)k_chain, dim3(128), dim3(256),
                               args, 0, stream);
  }
}

// Round 6
// 1333.977 us; speedup vs baseline: 1.2125x; 1.2125x over previous
//
#include <hip/hip_runtime.h>
#include <stdint.h>

#define B_ROWS 131072
#define SCALE 0.0625f
#define LN_EPS 1e-5f
#define ATTN_EPS 1e-8f

#define BIG_BLOCKS 768            // 3 blocks/CU x 256 CUs exactly
#define TOT_WAVES (BIG_BLOCKS*4)  // 3072

// ---- workspace layout (float offsets) ----
#define WS_PARTU 0                     // 768*4096 = 3145728
#define WS_PARTS 3145728               // 768*16   = 12288
#define WS_U     3158016               // 4096
#define WS_S     3162112               // 64
#define WS_SLOTS 3162176               // 4096
#define WS_GX    3166272               // 12288
#define WS_GH    3178560               // 12288
#define WS_H1    3190848               // 4096
#define WS_QKG   3194944               // 4096
#define WS_QB    3199040               // 64
#define WS_WIHV  3199104               // 196608
#define WS_BGX   3395712               // 768
#define WS_WQKG  3396480               // 65536
#define WS_U2G   3462016               // 256
#define WS_U1    3462272               // 256
#define WS_C1    3462528               // 1
// total ~3462529 floats ~ 13.9 MB

// =====================================================================
// K_pre1: weight compositions (fp32 inputs)
//  bid<48 : W_ihv[j][d] = sum_dd W_ih[j][dd]*Wv[dd][d]  (16 rows/block)
//           bgx[j] = b_ih[j] + W_ih[j]·bv
//  48..79 : WqkgT[c][d] = SCALE*g_in[c]*sum_i Wq[i][d]*Wk[i][c] (8 rows/block)
//           u2g[c] = SCALE*g_in[c]*sum_i bq[i]*Wk[i][c]
//  ==80   : u1[d] = sum_i Wq[i][d]*(bk[i]+Wk[i]·be_in),  c1 = bq·(bk+wkbe)
// =====================================================================
__global__ __launch_bounds__(256) void k_pre1(
    const float* __restrict__ Wq, const float* __restrict__ bq,
    const float* __restrict__ Wk, const float* __restrict__ bk,
    const float* __restrict__ Wv, const float* __restrict__ bv,
    const float* __restrict__ W_ih, const float* __restrict__ b_ih,
    const float* __restrict__ g_in, const float* __restrict__ be_in,
    float* __restrict__ ws)
{
  int bid = blockIdx.x, t = threadIdx.x;
  if (bid < 48) {
    int j0 = bid * 16;
    float acc[16];
#pragma unroll
    for (int r = 0; r < 16; r++) acc[r] = 0.f;
    int d = t;
    for (int dd = 0; dd < 256; dd++) {
      float v = Wv[dd * 256 + d];
#pragma unroll
      for (int r = 0; r < 16; r++)
        acc[r] = fmaf(W_ih[(j0 + r) * 256 + dd], v, acc[r]);
    }
#pragma unroll
    for (int r = 0; r < 16; r++) ws[WS_WIHV + (j0 + r) * 256 + d] = acc[r];
    if (t < 16) {
      int j = j0 + t;
      float a = b_ih[j];
      for (int dd = 0; dd < 256; dd++)
        a = fmaf(W_ih[j * 256 + dd], bv[dd], a);
      ws[WS_BGX + j] = a;
    }
  } else if (bid < 80) {
    int c0 = (bid - 48) * 8;
    float acc[8];
#pragma unroll
    for (int r = 0; r < 8; r++) acc[r] = 0.f;
    int d = t;
    for (int i = 0; i < 256; i++) {
      float wq = Wq[i * 256 + d];
#pragma unroll
      for (int r = 0; r < 8; r++)
        acc[r] = fmaf(wq, Wk[i * 256 + c0 + r], acc[r]);
    }
#pragma unroll
    for (int r = 0; r < 8; r++) {
      float gc = g_in[c0 + r];
      ws[WS_WQKG + (c0 + r) * 256 + d] = SCALE * gc * acc[r];
    }
    if (t < 8) {
      int c = c0 + t;
      float a = 0.f;
      for (int i = 0; i < 256; i++)
        a = fmaf(bq[i], Wk[i * 256 + c], a);
      ws[WS_U2G + c] = SCALE * g_in[c] * a;
    }
  } else {
    __shared__ __align__(16) float t2[256];
    int j = t;
    float a = 0.f;
    for (int dp = 0; dp < 256; dp++)
      a = fmaf(Wk[j * 256 + dp], be_in[dp], a);
    t2[j] = a + bk[j];
    __syncthreads();
    int d = t;
    float u = 0.f;
    for (int i = 0; i < 256; i++)
      u = fmaf(Wq[i * 256 + d], t2[i], u);
    ws[WS_U1 + d] = u;
    if (t == 0) {
      float c = 0.f;
      for (int i = 0; i < 256; i++) c = fmaf(bq[i], t2[i], c);
      ws[WS_C1] = c;
    }
  }
}

// =====================================================================
// K_qkg (init only): slots = mu + sigma*noise; LN(g_s,be_s); qkg, qb.
// =====================================================================
__global__ __launch_bounds__(256) void k_qkg(
    const float* __restrict__ noise, const float* __restrict__ mu,
    const float* __restrict__ sigma, const float* __restrict__ g_s,
    const float* __restrict__ be_s, float* __restrict__ ws)
{
  __shared__ __align__(16) float sS[16 * 260];
  __shared__ __align__(16) float sAux[512];
  __shared__ __align__(16) float sStat[32];
  int bid = blockIdx.x, t = threadIdx.x;
  for (int n = 0; n < 16; n++) {
    float v = fmaf(sigma[t], noise[n * 256 + t], mu[t]);
    sS[n * 260 + t] = v;
    if (bid == 0) ws[WS_SLOTS + n * 256 + t] = v;
  }
  __syncthreads();
  { int n = t >> 4, c = t & 15;
    float s1 = 0.f, s2 = 0.f;
    for (int k = 0; k < 16; k++) {
      float x = sS[n * 260 + c * 16 + k];
      s1 += x; s2 = fmaf(x, x, s2);
    }
    sAux[n * 16 + c] = s1; sAux[256 + n * 16 + c] = s2; }
  __syncthreads();
  if (t < 16) {
    float s1 = 0.f, s2 = 0.f;
    for (int c = 0; c < 16; c++) { s1 += sAux[t * 16 + c]; s2 += sAux[256 + t * 16 + c]; }
    float m = s1 * (1.f / 256.f);
    float v = fmaxf(fmaf(-m, m, s2 * (1.f / 256.f)), 0.f);
    sStat[t] = m; sStat[16 + t] = rsqrtf(v + LN_EPS);
  }
  __syncthreads();
  { float gs = g_s[t], bs = be_s[t];
    for (int n = 0; n < 16; n++) {
      float m = sStat[n], rs = sStat[16 + n];
      sS[n * 260 + t] = fmaf((sS[n * 260 + t] - m) * rs, gs, bs);
    } }
  __syncthreads();
  if (bid < 64) {
    int cr = t >> 6, n = (t >> 2) & 15, ks = t & 3;
    int c = bid * 4 + cr;
    const float* wrow = ws + WS_WQKG + c * 256 + ks * 64;
    const float* srow = &sS[n * 260 + ks * 64];
    float acc = 0.f;
#pragma unroll
    for (int i = 0; i < 16; i++) {
      float4 w = *(const float4*)(wrow + i * 4);
      float4 s4 = *(const float4*)(srow + i * 4);
      acc = fmaf(w.x, s4.x, fmaf(w.y, s4.y, fmaf(w.z, s4.z, fmaf(w.w, s4.w, acc))));
    }
    sAux[t] = acc;
    __syncthreads();
    if (t < 64) {
      int cr2 = t >> 4, n2 = t & 15;
      int c2 = bid * 4 + cr2;
      int b = cr2 * 64 + n2 * 4;
      float s = sAux[b] + sAux[b + 1] + sAux[b + 2] + sAux[b + 3];
      ws[WS_QKG + n2 * 256 + c2] = s + ws[WS_U2G + c2];
    }
  } else {
    int n = t >> 4, ks = t & 15;
    float acc = 0.f;
    for (int k = 0; k < 16; k++)
      acc = fmaf(sS[n * 260 + ks * 16 + k], ws[WS_U1 + ks * 16 + k], acc);
    sAux[t] = acc;
    __syncthreads();
    if (t < 16) {
      float s = 0.f;
      for (int k = 0; k < 16; k++) s += sAux[t * 16 + k];
      ws[WS_QB + t] = SCALE * (s + ws[WS_C1]);
    }
  }
}

// =====================================================================
// K_big: wave-per-row. launch_bounds(256,3): ~170-reg budget -> no scratch
// spills (R4/R5's (256,4) spilled: FETCH 920MB). No manual prefetch (saves
// 16 regs); wave-level grid-stride over rows. Combined 6-value butterfly.
// Epilogue: 16KB LDS 4-round accumulate + plain partial-slice store.
// =====================================================================
__global__ __launch_bounds__(256, 3) void k_big(
    const float* __restrict__ X, float* __restrict__ ws)
{
  __shared__ __align__(16) float red[16 * 256];   // 16 KB
  __shared__ __align__(16) float redS[64];
  int t = threadIdx.x;
  int wave = t >> 6, lane = t & 63;
  int p = lane >> 4, g = lane & 15;

  const float* qkg = ws + WS_QKG;
  float qw[4][16];
  float qs[4];
#pragma unroll
  for (int i = 0; i < 4; i++) {
    const float* rp = qkg + (4 * p + i) * 256 + g * 16;
#pragma unroll
    for (int jq = 0; jq < 4; jq++) {
      float4 v4 = *(const float4*)(rp + 4 * jq);
      qw[i][4 * jq + 0] = v4.x; qw[i][4 * jq + 1] = v4.y;
      qw[i][4 * jq + 2] = v4.z; qw[i][4 * jq + 3] = v4.w;
    }
    float s = 0.f;
#pragma unroll
    for (int j = 0; j < 16; j++) s += qw[i][j];
    qs[i] = s;
  }
#pragma unroll
  for (int m = 1; m <= 8; m <<= 1) {
#pragma unroll
    for (int i = 0; i < 4; i++) qs[i] += __shfl_xor(qs[i], m);
  }
  float qb0[4];
  {
    float4 q4 = *(const float4*)(ws + WS_QB + 4 * p);
    qb0[0] = q4.x; qb0[1] = q4.y; qb0[2] = q4.z; qb0[3] = q4.w;
  }

  float P[4][16];
#pragma unroll
  for (int i = 0; i < 4; i++)
#pragma unroll
    for (int j = 0; j < 16; j++) P[i][j] = 0.f;
  float Q[4] = {0.f, 0.f, 0.f, 0.f};
  float Sa[4] = {0.f, 0.f, 0.f, 0.f};

  int gw = blockIdx.x * 4 + wave;     // 0..3071

#pragma unroll 1
  for (int r = gw; r < B_ROWS; r += TOT_WAVES) {
    const float* row = X + (size_t)r * 256 + g * 16;
    float4 va = *(const float4*)row;
    float4 vb = *(const float4*)(row + 4);
    float4 vc = *(const float4*)(row + 8);
    float4 vd = *(const float4*)(row + 12);

    float x[16];
    x[0] = va.x; x[1] = va.y; x[2] = va.z; x[3] = va.w;
    x[4] = vb.x; x[5] = vb.y; x[6] = vb.z; x[7] = vb.w;
    x[8] = vc.x; x[9] = vc.y; x[10] = vc.z; x[11] = vc.w;
    x[12] = vd.x; x[13] = vd.y; x[14] = vd.z; x[15] = vd.w;

    float s1 = 0.f, s2 = 0.f;
    float d0 = 0.f, d1 = 0.f, d2 = 0.f, d3 = 0.f;
#pragma unroll
    for (int j = 0; j < 16; j++) {
      s1 += x[j]; s2 = fmaf(x[j], x[j], s2);
      d0 = fmaf(qw[0][j], x[j], d0);
      d1 = fmaf(qw[1][j], x[j], d1);
      d2 = fmaf(qw[2][j], x[j], d2);
      d3 = fmaf(qw[3][j], x[j], d3);
    }
    // one combined 4-step butterfly for all 6 partials
#pragma unroll
    for (int m = 1; m <= 8; m <<= 1) {
      s1 += __shfl_xor(s1, m); s2 += __shfl_xor(s2, m);
      d0 += __shfl_xor(d0, m); d1 += __shfl_xor(d1, m);
      d2 += __shfl_xor(d2, m); d3 += __shfl_xor(d3, m);
    }
    float mean = s1 * (1.f / 256.f);
    float var = fmaxf(fmaf(-mean, mean, s2 * (1.f / 256.f)), 0.f);
    float rs = rsqrtf(var + LN_EPS);
    float mrs = mean * rs;

    float dsc[4];
    dsc[0] = fmaf(rs, d0, fmaf(-mrs, qs[0], qb0[0]));
    dsc[1] = fmaf(rs, d1, fmaf(-mrs, qs[1], qb0[1]));
    dsc[2] = fmaf(rs, d2, fmaf(-mrs, qs[2], qb0[2]));
    dsc[3] = fmaf(rs, d3, fmaf(-mrs, qs[3], qb0[3]));

    float mx = fmaxf(fmaxf(dsc[0], dsc[1]), fmaxf(dsc[2], dsc[3]));
    mx = fmaxf(mx, __shfl_xor(mx, 16));
    mx = fmaxf(mx, __shfl_xor(mx, 32));
    float e0 = __expf(dsc[0] - mx), e1 = __expf(dsc[1] - mx);
    float e2 = __expf(dsc[2] - mx), e3 = __expf(dsc[3] - mx);
    float se = e0 + e1 + e2 + e3;
    se += __shfl_xor(se, 16);
    se += __shfl_xor(se, 32);
    float inv = 1.0f / se;
    float a0[4], ar[4];
    a0[0] = fmaf(e0, inv, ATTN_EPS); a0[1] = fmaf(e1, inv, ATTN_EPS);
    a0[2] = fmaf(e2, inv, ATTN_EPS); a0[3] = fmaf(e3, inv, ATTN_EPS);
#pragma unroll
    for (int i = 0; i < 4; i++) ar[i] = a0[i] * rs;
#pragma unroll
    for (int j = 0; j < 16; j++) {
      P[0][j] = fmaf(ar[0], x[j], P[0][j]);
      P[1][j] = fmaf(ar[1], x[j], P[1][j]);
      P[2][j] = fmaf(ar[2], x[j], P[2][j]);
      P[3][j] = fmaf(ar[3], x[j], P[3][j]);
    }
#pragma unroll
    for (int i = 0; i < 4; i++) {
      Q[i] = fmaf(a0[i], mrs, Q[i]);
      Sa[i] += a0[i];
    }
  }

  // ---- epilogue: block-reduce U = P - Q into 16KB LDS, plain store ----
  if (g == 0) {
#pragma unroll
    for (int i = 0; i < 4; i++) redS[wave * 16 + 4 * p + i] = Sa[i];
  }
#pragma unroll 1
  for (int w = 0; w < 4; w++) {
    if (w) __syncthreads();
    if (wave == w) {
#pragma unroll
      for (int i = 0; i < 4; i++) {
#pragma unroll
        for (int jq = 0; jq < 4; jq++) {
          int idx = (4 * p + i) * 256 + g * 16 + jq * 4;
          float4 v4;
          v4.x = P[i][4 * jq + 0] - Q[i]; v4.y = P[i][4 * jq + 1] - Q[i];
          v4.z = P[i][4 * jq + 2] - Q[i]; v4.w = P[i][4 * jq + 3] - Q[i];
          if (w == 0) {
            *(float4*)&red[idx] = v4;
          } else {
            float4 o = *(const float4*)&red[idx];
            v4.x += o.x; v4.y += o.y; v4.z += o.z; v4.w += o.w;
            *(float4*)&red[idx] = v4;
          }
        }
      }
    }
  }
  __syncthreads();
#pragma unroll
  for (int k = 0; k < 16; k++) {
    int idx = k * 256 + t;
    ws[WS_PARTU + (size_t)blockIdx.x * 4096 + idx] = red[idx];
  }
  if (t < 16) {
    float sv = redS[t] + redS[16 + t] + redS[32 + t] + redS[48 + t];
    ws[WS_PARTS + blockIdx.x * 16 + t] = sv;
  }
}

// =====================================================================
// K_chainA (192 blocks): bid<128 -> reduce 768 partial slices to U
// (bid 127 also S); bid>=128 -> gh[n][j] = W_hh[j]·slots_prev[n]+b_hh[j]
// =====================================================================
__global__ __launch_bounds__(256) void k_chainA(
    const float* __restrict__ W_hh, const float* __restrict__ b_hh,
    float* __restrict__ ws)
{
  __shared__ __align__(16) float sRed[256];
  __shared__ __align__(16) float sAux[256];
  __shared__ __align__(16) float sBuf[16 * 260];
  int bid = blockIdx.x, t = threadIdx.x;
  if (bid < 128) {
    int el = t & 31, wg = t >> 5;      // 8 groups x 96 slices
    int e = bid * 32 + el;
    float acc = 0.f;
#pragma unroll 8
    for (int k = 0; k < 96; k++)
      acc += ws[WS_PARTU + (size_t)(wg * 96 + k) * 4096 + e];
    sRed[t] = acc;
    float a = 0.f;
    if (bid == 127) {
      int n = t & 15, wg2 = t >> 4;    // 16 groups x 48 slices
      for (int k = 0; k < 48; k++)
        a += ws[WS_PARTS + (wg2 * 48 + k) * 16 + n];
    }
    sAux[t] = a;
    __syncthreads();
    if (t < 32) {
      float s = 0.f;
#pragma unroll
      for (int w = 0; w < 8; w++) s += sRed[w * 32 + t];
      ws[WS_U + bid * 32 + t] = s;
    }
    if (bid == 127 && t < 16) {
      float s = 0.f;
#pragma unroll
      for (int w = 0; w < 16; w++) s += sAux[w * 16 + t];
      ws[WS_S + t] = s;
    }
  } else {
    for (int n = 0; n < 16; n++)
      sBuf[n * 260 + t] = ws[WS_SLOTS + n * 256 + t];
    __syncthreads();
    int jr = t >> 4, n = t & 15;
    if (jr < 12) {
      int j = (bid - 128) * 12 + jr;
      const float* srow = &sBuf[n * 260];
      const float* wrow = W_hh + j * 256;
      float acc = b_hh[j];
#pragma unroll 8
      for (int k = 0; k < 64; k++) {
        float4 w = *(const float4*)(wrow + k * 4);
        float4 s4 = *(const float4*)(srow + k * 4);
        acc = fmaf(w.x, s4.x, fmaf(w.y, s4.y, fmaf(w.z, s4.z, fmaf(w.w, s4.w, acc))));
      }
      ws[WS_GH + n * 768 + j] = acc;
    }
  }
}

// =====================================================================
// K_chainB (1 block x 1024 threads): gx GEMM, GRU->mid, LN(g_f), h1,
// ff -> slots/out, and (if !last) LN(g_s)+qkg/qb for the next iteration.
// =====================================================================
__device__ __forceinline__ float gru1(float xr, float hr, float xz, float hz,
                                      float xn, float hn, float sp) {
  float r = 1.f / (1.f + __expf(-(xr + hr)));
  float z = 1.f / (1.f + __expf(-(xz + hz)));
  float nn = tanhf(fmaf(r, hn, xn));
  return fmaf(z, sp - nn, nn);
}

__global__ __launch_bounds__(1024) void k_chainB(
    const float* __restrict__ W1, const float* __restrict__ b1,
    const float* __restrict__ g_f, const float* __restrict__ be_f,
    const float* __restrict__ W2, const float* __restrict__ b2v,
    const float* __restrict__ g_in, const float* __restrict__ be_in,
    const float* __restrict__ g_s, const float* __restrict__ be_s,
    float* __restrict__ out, float* __restrict__ ws, int last)
{
  __shared__ __align__(16) float sSlots[16 * 260];
  __shared__ __align__(16) float sB[16 * 260];     // uln -> lnf -> lnS
  __shared__ __align__(16) float sMid[16 * 260];
  __shared__ __align__(16) float sStat[16];
  int t = threadIdx.x;
  int nw = t >> 6, lw = t & 63;        // wave-slot layout (16 x 64)

  if (t < 16) sStat[t] = 1.0f / ws[WS_S + t];
  {
    float4 sp = *(const float4*)(ws + WS_SLOTS + nw * 256 + lw * 4);
    *(float4*)&sSlots[nw * 260 + lw * 4] = sp;
  }
  __syncthreads();
  // uln = g_in * U/S + be_in
  {
    int d = lw * 4;
    float inv = sStat[nw];
    float4 u = *(const float4*)(ws + WS_U + nw * 256 + d);
    float4 gi = *(const float4*)(g_in + d);
    float4 bi = *(const float4*)(be_in + d);
    float4 r;
    r.x = fmaf(gi.x * u.x, inv, bi.x);
    r.y = fmaf(gi.y * u.y, inv, bi.y);
    r.z = fmaf(gi.z * u.z, inv, bi.z);
    r.w = fmaf(gi.w * u.w, inv, bi.w);
    *(float4*)&sB[nw * 260 + d] = r;
  }
  __syncthreads();
  // gx: thread (n = t&15, jg = t>>4): 12 j-rows, k-tiled (8 x 32)
  {
    int n = t & 15, jg = t >> 4;
    int j0 = jg * 12;
    float acc[12];
#pragma unroll
    for (int jj = 0; jj < 12; jj++) acc[jj] = ws[WS_BGX + j0 + jj];
#pragma unroll 1
    for (int kt = 0; kt < 8; kt++) {
      float4 u[8];
#pragma unroll
      for (int i = 0; i < 8; i++)
        u[i] = *(const float4*)&sB[n * 260 + kt * 32 + i * 4];
#pragma unroll
      for (int jj = 0; jj < 12; jj++) {
        const float* wrow = ws + WS_WIHV + (size_t)(j0 + jj) * 256 + kt * 32;
        float a = acc[jj];
#pragma unroll
        for (int i = 0; i < 8; i++) {
          float4 w = *(const float4*)(wrow + i * 4);
          a = fmaf(w.x, u[i].x, fmaf(w.y, u[i].y, fmaf(w.z, u[i].z, fmaf(w.w, u[i].w, a))));
        }
        acc[jj] = a;
      }
    }
#pragma unroll
    for (int jj = 0; jj < 12; jj++) ws[WS_GX + n * 768 + j0 + jj] = acc[jj];
  }
  __syncthreads();
  // GRU -> mid (sMid); wave nw owns slot nw; LN(g_f) -> lnf (sB)
  {
    int d = lw * 4;
    const float* gx = ws + WS_GX + nw * 768;
    const float* gh = ws + WS_GH + nw * 768;
    float4 xr = *(const float4*)(gx + d);
    float4 xz = *(const float4*)(gx + 256 + d);
    float4 xn = *(const float4*)(gx + 512 + d);
    float4 hr = *(const float4*)(gh + d);
    float4 hz = *(const float4*)(gh + 256 + d);
    float4 hn = *(const float4*)(gh + 512 + d);
    float4 sp = *(const float4*)&sSlots[nw * 260 + d];
    float4 mid;
    mid.x = gru1(xr.x, hr.x, xz.x, hz.x, xn.x, hn.x, sp.x);
    mid.y = gru1(xr.y, hr.y, xz.y, hz.y, xn.y, hn.y, sp.y);
    mid.z = gru1(xr.z, hr.z, xz.z, hz.z, xn.z, hn.z, sp.z);
    mid.w = gru1(xr.w, hr.w, xz.w, hz.w, xn.w, hn.w, sp.w);
    *(float4*)&sMid[nw * 260 + d] = mid;
    float s1 = mid.x + mid.y + mid.z + mid.w;
    float s2 = fmaf(mid.x, mid.x, fmaf(mid.y, mid.y, fmaf(mid.z, mid.z, mid.w * mid.w)));
#pragma unroll
    for (int m = 1; m <= 32; m <<= 1) {
      s1 += __shfl_xor(s1, m);
      s2 += __shfl_xor(s2, m);
    }
    float mean = s1 * (1.f / 256.f);
    float var = fmaxf(fmaf(-mean, mean, s2 * (1.f / 256.f)), 0.f);
    float rs = rsqrtf(var + LN_EPS);
    float4 gf = *(const float4*)(g_f + d);
    float4 bf = *(const float4*)(be_f + d);
    float4 lf;
    lf.x = fmaf((mid.x - mean) * rs, gf.x, bf.x);
    lf.y = fmaf((mid.y - mean) * rs, gf.y, bf.y);
    lf.z = fmaf((mid.z - mean) * rs, gf.z, bf.z);
    lf.w = fmaf((mid.w - mean) * rs, gf.w, bf.w);
    *(float4*)&sB[nw * 260 + d] = lf;
  }
  __syncthreads();
  // h1 = relu(lnf @ W1.T + b1): thread (n = t&15, hg = t>>4): 4 h-rows
  {
    int n = t & 15, hg = t >> 4;
    int h0 = hg * 4;
    float acc[4] = {0.f, 0.f, 0.f, 0.f};
#pragma unroll 1
    for (int k4 = 0; k4 < 64; k4++) {
      float4 l4 = *(const float4*)&sB[n * 260 + k4 * 4];
#pragma unroll
      for (int hh = 0; hh < 4; hh++) {
        float4 w = *(const float4*)(W1 + (size_t)(h0 + hh) * 256 + k4 * 4);
        acc[hh] = fmaf(w.x, l4.x, fmaf(w.y, l4.y, fmaf(w.z, l4.z, fmaf(w.w, l4.w, acc[hh]))));
      }
    }
#pragma unroll
    for (int hh = 0; hh < 4; hh++)
      ws[WS_H1 + n * 256 + h0 + hh] = fmaxf(acc[hh] + b1[h0 + hh], 0.f);
  }
  __syncthreads();
  // ff = h1 @ W2.T + b2; slots_new = mid + ff -> sSlots, ws, out
  {
    int n = t & 15, dg = t >> 4;
    int d0 = dg * 4;
    float acc[4] = {0.f, 0.f, 0.f, 0.f};
#pragma unroll 1
    for (int k4 = 0; k4 < 64; k4++) {
      float4 h4 = *(const float4*)(ws + WS_H1 + n * 256 + k4 * 4);
#pragma unroll
      for (int dd = 0; dd < 4; dd++) {
        float4 w = *(const float4*)(W2 + (size_t)(d0 + dd) * 256 + k4 * 4);
        acc[dd] = fmaf(w.x, h4.x, fmaf(w.y, h4.y, fmaf(w.z, h4.z, fmaf(w.w, h4.w, acc[dd]))));
      }
    }
    float4 mid = *(const float4*)&sMid[n * 260 + d0];
    float4 b2f4 = *(const float4*)(b2v + d0);
    float4 v;
    v.x = acc[0] + b2f4.x + mid.x;
    v.y = acc[1] + b2f4.y + mid.y;
    v.z = acc[2] + b2f4.z + mid.z;
    v.w = acc[3] + b2f4.w + mid.w;
    *(float4*)&sSlots[n * 260 + d0] = v;
    *(float4*)(ws + WS_SLOTS + n * 256 + d0) = v;
    *(float4*)(out + n * 256 + d0) = v;
  }
  if (last) return;
  __syncthreads();
  // LN(g_s)(slots_new) -> lnS (sB); wave nw owns slot nw
  {
    int d = lw * 4;
    float4 v = *(const float4*)&sSlots[nw * 260 + d];
    float s1 = v.x + v.y + v.z + v.w;
    float s2 = fmaf(v.x, v.x, fmaf(v.y, v.y, fmaf(v.z, v.z, v.w * v.w)));
#pragma unroll
    for (int m = 1; m <= 32; m <<= 1) {
      s1 += __shfl_xor(s1, m);
      s2 += __shfl_xor(s2, m);
    }
    float mean = s1 * (1.f / 256.f);
    float var = fmaxf(fmaf(-mean, mean, s2 * (1.f / 256.f)), 0.f);
    float rs = rsqrtf(var + LN_EPS);
    float4 gs = *(const float4*)(g_s + d);
    float4 bs = *(const float4*)(be_s + d);
    float4 ln;
    ln.x = fmaf((v.x - mean) * rs, gs.x, bs.x);
    ln.y = fmaf((v.y - mean) * rs, gs.y, bs.y);
    ln.z = fmaf((v.z - mean) * rs, gs.z, bs.z);
    ln.w = fmaf((v.w - mean) * rs, gs.w, bs.w);
    *(float4*)&sB[nw * 260 + d] = ln;
  }
  __syncthreads();
  // qkg[n][c] = lnS[n] · WqkgT[c] + u2g[c]: thread (n, cg): 4 c-cols
  {
    int n = t & 15, cg = t >> 4;
    int c0 = cg * 4;
    float acc[4] = {0.f, 0.f, 0.f, 0.f};
#pragma unroll 1
    for (int k4 = 0; k4 < 64; k4++) {
      float4 l4 = *(const float4*)&sB[n * 260 + k4 * 4];
#pragma unroll
      for (int cc = 0; cc < 4; cc++) {
        float4 w = *(const float4*)(ws + WS_WQKG + (size_t)(c0 + cc) * 256 + k4 * 4);
        acc[cc] = fmaf(w.x, l4.x, fmaf(w.y, l4.y, fmaf(w.z, l4.z, fmaf(w.w, l4.w, acc[cc]))));
      }
    }
#pragma unroll
    for (int cc = 0; cc < 4; cc++)
      ws[WS_QKG + n * 256 + c0 + cc] = acc[cc] + ws[WS_U2G + c0 + cc];
  }
  // qb[n] = SCALE*(lnS[n]·u1 + c1)
  if (t < 16) {
    float acc = 0.f;
    for (int k4 = 0; k4 < 64; k4++) {
      float4 l4 = *(const float4*)&sB[t * 260 + k4 * 4];
      float4 u = *(const float4*)(ws + WS_U1 + k4 * 4);
      acc = fmaf(l4.x, u.x, fmaf(l4.y, u.y, fmaf(l4.z, u.z, fmaf(l4.w, u.w, acc))));
    }
    ws[WS_QB + t] = SCALE * (acc + ws[WS_C1]);
  }
}

// =====================================================================
extern "C" void kernel_launch(void* const* d_in, const int* in_sizes, int n_in,
                              void* d_out, int out_size, void* d_ws, size_t ws_size,
                              hipStream_t stream)
{
  (void)in_sizes; (void)n_in; (void)out_size; (void)ws_size;
  const float* inputs = (const float*)d_in[0];
  const float* noise  = (const float*)d_in[1];
  const float* mu     = (const float*)d_in[2];
  const float* sigma  = (const float*)d_in[3];
  const float* Wq     = (const float*)d_in[4];
  const float* bq     = (const float*)d_in[5];
  const float* Wk     = (const float*)d_in[6];
  const float* bk     = (const float*)d_in[7];
  const float* Wv     = (const float*)d_in[8];
  const float* bv     = (const float*)d_in[9];
  const float* W_ih   = (const float*)d_in[10];
  const float* W_hh   = (const float*)d_in[11];
  const float* b_ih   = (const float*)d_in[12];
  const float* b_hh   = (const float*)d_in[13];
  const float* W1     = (const float*)d_in[14];
  const float* b1     = (const float*)d_in[15];
  const float* W2     = (const float*)d_in[16];
  const float* b2     = (const float*)d_in[17];
  const float* g_in   = (const float*)d_in[18];
  const float* be_in  = (const float*)d_in[19];
  const float* g_s    = (const float*)d_in[20];
  const float* be_s   = (const float*)d_in[21];
  const float* g_f    = (const float*)d_in[22];
  const float* be_f   = (const float*)d_in[23];
  float* ws = (float*)d_ws;
  float* out = (float*)d_out;

  hipLaunchKernelGGL(k_pre1, dim3(81), dim3(256), 0, stream,
                     Wq, bq, Wk, bk, Wv, bv, W_ih, b_ih, g_in, be_in, ws);
  hipLaunchKernelGGL(k_qkg, dim3(65), dim3(256), 0, stream,
                     noise, mu, sigma, g_s, be_s, ws);
  for (int it = 0; it < 3; it++) {
    hipLaunchKernelGGL(k_big, dim3(BIG_BLOCKS), dim3(256), 0, stream, inputs, ws);
    hipLaunchKernelGGL(k_chainA, dim3(192), dim3(256), 0, stream,
                       W_hh, b_hh, ws);
    hipLaunchKernelGGL(k_chainB, dim3(1), dim3(1024), 0, stream,
                       W1, b1, g_f, be_f, W2, b2, g_in, be_in, g_s, be_s,
                       out, ws, (it == 2) ? 1 : 0);
  }
}